// Round 7
// baseline (271.695 us; speedup 1.0000x reference)
//
#include <hip/hip_runtime.h>

namespace {

constexpr int BATCH = 16;
constexpr int HH = 512;
constexpr int WW = 512;
constexpr int PLANE = HH * WW;

// ---- numpy-faithful cosine table construction ----------------------------
// Reference: i = arange(8, float32); cx = np.cos((2i+1)[:,None] * i[None,:] * np.pi / 16)
//   K = (2x+1)*u  (exact small int in f32)
//   t = fl32(K * fl32(pi))          <- scalar pi DEMOTED to f32 (numpy promotion)
//   angle = t / 16                  <- exact in f32
//   cx[x,u] = cos_f32(angle)        <- we model as fl32(cos_f64(widen(angle)))
// dct_T[x,y,u,v] = fl32( cx[x,u] * cx[y,v] )   <- f32 product

constexpr double PI64 = 3.141592653589793;              // fl64(pi)
constexpr double PI_LO = 1.2246467991473532e-16;        // pi - fl64(pi)
// split: PI_HI has <=46 mantissa bits so K*PI_HI (K<=105) is exact
constexpr double PI_HI = (double)((long long)(PI64 * 17592186044416.0)) / 17592186044416.0;
constexpr double PI_MID = PI64 - PI_HI;                 // exact remainder

// cos(k*pi/16) exact-table, k any int >= 0
constexpr double CD9[9] = {
    1.0,
    0.9807852804032304491,
    0.9238795325112867561,
    0.8314696123025452371,
    0.7071067811865475244,
    0.5555702330196022248,
    0.3826834323650897717,
    0.1950903220161282678,
    0.0};
constexpr double cos_tab(int m) {
    m %= 32;
    double s = 1.0;
    if (m > 16) m = 32 - m;
    if (m > 8) { s = -1.0; m = 16 - m; }
    return s * CD9[m];
}
constexpr double sin_tab(int m) { return cos_tab(m + 24); }  // sin(t)=cos(t-pi/2)

// f64 cosine of the f32-rounded angle: angle64 = widen(fl32(K*fl32(pi)))/16
constexpr double cx64(int K) {
    float Kf = (float)K;
    float p32 = (float)PI64;            // fl32(pi)
    float t32 = Kf * p32;               // fl32(K*pi32), round-to-nearest
    double F = (double)t32;             // exact widen; angle*16
    // r = angle - K*pi/16 = (F - K*pi)/16 ; F - K*PI_HI is exact (nearby exacts)
    double E = ((F - (double)K * PI_HI) - (double)K * PI_MID) - (double)K * PI_LO;
    double r = E / 16.0;                // |r| <~ 1e-6
    double C = cos_tab(K), S = sin_tab(K);
    double cr = 1.0 - 0.5 * r * r;
    double sr = r - (r * r * r) / 6.0;
    return C * cr - S * sr;             // abs err ~1e-20
}
constexpr float cx32(int x, int u) { return (float)cx64((2 * x + 1) * u); }

// dct table rows per (u,v), 64 contiguous (x,y) in ascending x*8+y order,
// f32 products widened to f64 (numpy promotion when contracting f64 data).
struct DctTbl { double t[64][64]; };
constexpr DctTbl make_dct() {
    DctTbl T{};
    for (int u = 0; u < 8; ++u)
        for (int v = 0; v < 8; ++v)
            for (int x = 0; x < 8; ++x)
                for (int y = 0; y < 8; ++y)
                    T.t[u * 8 + v][x * 8 + y] = (double)(cx32(x, u) * cx32(y, v));
    return T;
}
constexpr DctTbl DCTT = make_dct();

// fp32 cosines for the smooth separable IDCT epilogue (numpy-faithful values)
struct C32Tbl { float c[8][8]; };
constexpr C32Tbl make_c32() {
    C32Tbl t{};
    for (int x = 0; x < 8; ++x)
        for (int u = 0; u < 8; ++u)
            t.c[x][u] = cx32(x, u);
    return t;
}
constexpr C32Tbl C32 = make_c32();

constexpr float YQ[64] = {
    16, 11, 10, 16, 24, 40, 51, 61,
    12, 12, 14, 19, 26, 58, 60, 55,
    14, 13, 16, 24, 40, 57, 69, 56,
    14, 17, 22, 29, 51, 87, 80, 62,
    18, 22, 37, 56, 68, 109, 103, 77,
    24, 35, 55, 64, 81, 104, 113, 92,
    49, 64, 78, 87, 103, 121, 120, 101,
    72, 92, 95, 98, 112, 100, 103, 99};

constexpr float CQ[64] = {
    17, 18, 24, 47, 99, 99, 99, 99,
    18, 21, 26, 66, 99, 99, 99, 99,
    24, 26, 56, 99, 99, 99, 99, 99,
    47, 66, 99, 99, 99, 99, 99, 99,
    99, 99, 99, 99, 99, 99, 99, 99,
    99, 99, 99, 99, 99, 99, 99, 99,
    99, 99, 99, 99, 99, 99, 99, 99,
    99, 99, 99, 99, 99, 99, 99, 99};

constexpr float AL32 = (float)0.7071067811865475244;  // fl32(1/sqrt(2)), as ref

struct QuantTbl { double m[64]; double qtd[64]; double dq[64]; };
constexpr QuantTbl make_q(bool luma) {
    QuantTbl q{};
    for (int u = 0; u < 8; ++u)
        for (int v = 0; v < 8; ++v) {
            int i = u * 8 + v;
            float aa = (u == 0 ? AL32 : 1.0f) * (v == 0 ? AL32 : 1.0f);  // f32 outer
            float qt = luma ? YQ[i] : CQ[i];
            q.m[i]   = (double)(aa * 0.25f);     // widen(fl32(aa)*0.25) (exact *2^-2)
            q.qtd[i] = (double)qt;               // exact integer
            q.dq[i]  = (double)qt * (double)aa;  // post-decision dequant*alpha
        }
    return q;
}
constexpr QuantTbl QTY = make_q(true);
constexpr QuantTbl QTC = make_q(false);

} // namespace

// Level-shifted YCbCr channel CH of one 8x8 block in fp64; reference-faithful
// fp64 DCT (widened fp32 2D table) + diff_round quantize; output F[] fp32
// dequantized * alpha (post-decision, smooth from here on).
template <int CH>
__device__ __forceinline__ void process_channel(const float* __restrict__ in,
                                                size_t base, float* F) {
    double Yd[64];
    #pragma unroll
    for (int r = 0; r < 8; ++r) {
        float R[8], G[8], B[8];
        const float* p0 = in + base + (size_t)r * WW;
        *(float4*)&R[0] = *(const float4*)(p0);
        *(float4*)&R[4] = *(const float4*)(p0 + 4);
        *(float4*)&G[0] = *(const float4*)(p0 + PLANE);
        *(float4*)&G[4] = *(const float4*)(p0 + PLANE + 4);
        *(float4*)&B[0] = *(const float4*)(p0 + 2 * (size_t)PLANE);
        *(float4*)&B[4] = *(const float4*)(p0 + 2 * (size_t)PLANE + 4);
        #pragma unroll
        for (int c = 0; c < 8; ++c) {
            double rv = ((double)R[c] + 1.0) * 127.5;
            double gv = ((double)G[c] + 1.0) * 127.5;
            double bv = ((double)B[c] + 1.0) * 127.5;
            double v;
            if constexpr (CH == 0) {
                v = ((double)0.299f * rv + (double)0.587f * gv) + (double)0.114f * bv;
                v = v - 128.0;
            } else if constexpr (CH == 1) {
                v = ((double)-0.168736f * rv + (double)-0.331264f * gv) + (double)0.5f * bv;
                v = (v + 128.0) - 128.0;
            } else {
                v = ((double)0.5f * rv + (double)-0.418688f * gv) + (double)-0.081312f * bv;
                v = (v + 128.0) - 128.0;
            }
            Yd[r * 8 + c] = v;
        }
    }

    const QuantTbl& Q = (CH == 0) ? QTY : QTC;
    #pragma unroll 1
    for (int uv = 0; uv < 64; ++uv) {
        const double* t = DCTT.t[uv];
        double a0 = 0.0, a1 = 0.0, a2 = 0.0, a3 = 0.0;
        #pragma unroll
        for (int i = 0; i < 16; ++i) {
            a0 += t[i]      * Yd[i];
            a1 += t[i + 16] * Yd[i + 16];
            a2 += t[i + 32] * Yd[i + 32];
            a3 += t[i + 48] * Yd[i + 48];
        }
        double S = (a0 + a1) + (a2 + a3);
        double f = (Q.m[uv] * S) / Q.qtd[uv];   // true f64 divide by integer table
        double rr = __builtin_rint(f);          // half-to-even = np.round
        double d = f - rr;
        F[uv] = (float)((rr + (d * d) * d) * Q.dq[uv]);
    }
}

// Smooth separable fp32 IDCT in place; folds the 0.25.
__device__ __forceinline__ void idct_inplace(float* F) {
    #pragma unroll
    for (int u = 0; u < 8; ++u) {    // contract v -> y
        float t[8];
        #pragma unroll
        for (int y = 0; y < 8; ++y) {
            float s = 0.0f;
            #pragma unroll
            for (int v = 0; v < 8; ++v) s += C32.c[y][v] * F[u * 8 + v];
            t[y] = s;
        }
        #pragma unroll
        for (int y = 0; y < 8; ++y) F[u * 8 + y] = t[y];
    }
    #pragma unroll
    for (int y = 0; y < 8; ++y) {    // contract u -> x, fold 0.25
        float t[8];
        #pragma unroll
        for (int x = 0; x < 8; ++x) {
            float s = 0.0f;
            #pragma unroll
            for (int u = 0; u < 8; ++u) s += C32.c[x][u] * F[u * 8 + y];
            t[x] = s;
        }
        #pragma unroll
        for (int x = 0; x < 8; ++x) F[x * 8 + y] = 0.25f * t[x];
    }
}

// One thread = one spatial 8x8 block; fp32 in / fp32 out; fp64 through the
// quantizer's rounding decision, fp32 afterwards.
__global__ __launch_bounds__(256, 1) void jpeg_kernel(const float* __restrict__ in,
                                                      float* __restrict__ out) {
    const int tid = blockIdx.x * blockDim.x + threadIdx.x;  // 0..65535
    const int b = tid >> 12;
    const int blk = tid & 4095;
    const int by = blk >> 6;
    const int bx = blk & 63;
    const size_t base = (size_t)b * 3 * PLANE + (size_t)(by * 8) * WW + (size_t)(bx * 8);

    float F0[64], F1[64], F2[64];
    process_channel<0>(in, base, F0);
    idct_inplace(F0);
    process_channel<1>(in, base, F1);
    idct_inplace(F1);
    process_channel<2>(in, base, F2);
    idct_inplace(F2);

    // YCbCr -> RGB, clip, /255, fp32 stores.
    // Y's +128 applied here; Cb/Cr's +128 (idct) cancels the -128 (ycc shift).
    #pragma unroll
    for (int r = 0; r < 8; ++r) {
        float o[3][8];
        #pragma unroll
        for (int c = 0; c < 8; ++c) {
            int i = r * 8 + c;
            float yv = F0[i] + 128.0f;
            float cb = F1[i];
            float cr = F2[i];
            float rv = yv + 1.402f * cr;
            float gv = yv - 0.344136f * cb - 0.714136f * cr;
            float bv = yv + 1.772f * cb;
            o[0][c] = fminf(fmaxf(rv, 0.0f), 255.0f) * (1.0f / 255.0f);
            o[1][c] = fminf(fmaxf(gv, 0.0f), 255.0f) * (1.0f / 255.0f);
            o[2][c] = fminf(fmaxf(bv, 0.0f), 255.0f) * (1.0f / 255.0f);
        }
        #pragma unroll
        for (int ch = 0; ch < 3; ++ch) {
            float4* dst = (float4*)(out + base + (size_t)ch * PLANE + (size_t)r * WW);
            dst[0] = make_float4(o[ch][0], o[ch][1], o[ch][2], o[ch][3]);
            dst[1] = make_float4(o[ch][4], o[ch][5], o[ch][6], o[ch][7]);
        }
    }
}

extern "C" void kernel_launch(void* const* d_in, const int* in_sizes, int n_in,
                              void* d_out, int out_size, void* d_ws, size_t ws_size,
                              hipStream_t stream) {
    const float* in = (const float*)d_in[0];
    float* out = (float*)d_out;
    const int nthreads = BATCH * (HH / 8) * (WW / 8);
    jpeg_kernel<<<nthreads / 256, 256, 0, stream>>>(in, out);
}

// Round 8
// 187.285 us; speedup vs baseline: 1.4507x; 1.4507x over previous
//
#include <hip/hip_runtime.h>

namespace {

constexpr int BATCH = 16;
constexpr int HH = 512;
constexpr int WW = 512;
constexpr int PLANE = HH * WW;
constexpr int NBLK = BATCH * (HH / 8) * (WW / 8);  // 65536 spatial 8x8 blocks
constexpr int NWG = 2048;                          // 64-thread workgroups (1 wave)
constexpr int ITERS = NBLK / NWG;                  // 32 blocks per wave

// ---- numpy-faithful cosine table (DO NOT TOUCH — decision-path numerics) ----
// cx[x,u] = fl32( cos( widen(fl32(K * fl32(pi))) / 16 ) ), K = (2x+1)*u
// dct_T[x,y,u,v] = fl32( cx[x,u] * cx[y,v] ), widened to f64 for contraction.
constexpr double PI64 = 3.141592653589793;
constexpr double PI_LO = 1.2246467991473532e-16;
constexpr double PI_HI = (double)((long long)(PI64 * 17592186044416.0)) / 17592186044416.0;
constexpr double PI_MID = PI64 - PI_HI;

constexpr double CD9[9] = {
    1.0,
    0.9807852804032304491,
    0.9238795325112867561,
    0.8314696123025452371,
    0.7071067811865475244,
    0.5555702330196022248,
    0.3826834323650897717,
    0.1950903220161282678,
    0.0};
constexpr double cos_tab(int m) {
    m %= 32;
    double s = 1.0;
    if (m > 16) m = 32 - m;
    if (m > 8) { s = -1.0; m = 16 - m; }
    return s * CD9[m];
}
constexpr double sin_tab(int m) { return cos_tab(m + 24); }

constexpr double cx64(int K) {
    float Kf = (float)K;
    float p32 = (float)PI64;
    float t32 = Kf * p32;
    double F = (double)t32;
    double E = ((F - (double)K * PI_HI) - (double)K * PI_MID) - (double)K * PI_LO;
    double r = E / 16.0;
    double C = cos_tab(K), S = sin_tab(K);
    double cr = 1.0 - 0.5 * r * r;
    double sr = r - (r * r * r) / 6.0;
    return C * cr - S * sr;
}
constexpr float cx32(int x, int u) { return (float)cx64((2 * x + 1) * u); }

// DCT table: row per (u,v)=uv, 64 contiguous (x,y) entries, widened f32 products
struct DctTbl { double t[64][64]; };
constexpr DctTbl make_dct() {
    DctTbl T{};
    for (int u = 0; u < 8; ++u)
        for (int v = 0; v < 8; ++v)
            for (int x = 0; x < 8; ++x)
                for (int y = 0; y < 8; ++y)
                    T.t[u * 8 + v][x * 8 + y] = (double)(cx32(x, u) * cx32(y, v));
    return T;
}
constexpr DctTbl DCTT = make_dct();

// fp32 cosines c[x][u] flattened for the smooth IDCT (LDS-resident at runtime)
struct C32A { float c[64]; };
constexpr C32A make_c32f() {
    C32A a{};
    for (int x = 0; x < 8; ++x)
        for (int u = 0; u < 8; ++u)
            a.c[x * 8 + u] = cx32(x, u);
    return a;
}
constexpr C32A C32F = make_c32f();

constexpr float YQ[64] = {
    16, 11, 10, 16, 24, 40, 51, 61,
    12, 12, 14, 19, 26, 58, 60, 55,
    14, 13, 16, 24, 40, 57, 69, 56,
    14, 17, 22, 29, 51, 87, 80, 62,
    18, 22, 37, 56, 68, 109, 103, 77,
    24, 35, 55, 64, 81, 104, 113, 92,
    49, 64, 78, 87, 103, 121, 120, 101,
    72, 92, 95, 98, 112, 100, 103, 99};

constexpr float CQ[64] = {
    17, 18, 24, 47, 99, 99, 99, 99,
    18, 21, 26, 66, 99, 99, 99, 99,
    24, 26, 56, 99, 99, 99, 99, 99,
    47, 66, 99, 99, 99, 99, 99, 99,
    99, 99, 99, 99, 99, 99, 99, 99,
    99, 99, 99, 99, 99, 99, 99, 99,
    99, 99, 99, 99, 99, 99, 99, 99,
    99, 99, 99, 99, 99, 99, 99, 99};

constexpr float AL32 = (float)0.7071067811865475244;

// Per-coefficient quant scalars (indexed by uv = lane), identical to R7 values
struct QuantD { double m[64]; double qty[64]; double qtc[64]; double dqy[64]; double dqc[64]; };
constexpr QuantD make_qd() {
    QuantD q{};
    for (int u = 0; u < 8; ++u)
        for (int v = 0; v < 8; ++v) {
            int i = u * 8 + v;
            float aa = (u == 0 ? AL32 : 1.0f) * (v == 0 ? AL32 : 1.0f);
            q.m[i]   = (double)(aa * 0.25f);
            q.qty[i] = (double)YQ[i];
            q.qtc[i] = (double)CQ[i];
            q.dqy[i] = (double)YQ[i] * (double)aa;
            q.dqc[i] = (double)CQ[i] * (double)aa;
        }
    return q;
}
constexpr QuantD QD = make_qd();

} // namespace

// Wave-per-block: 64 lanes = 64 pixels (load/color/idct/store) and
// 64 (u,v) coefficients (DCT dot / quant). Table row per lane in VGPRs;
// spatial values broadcast from LDS. No per-thread arrays -> no scratch.
__global__ __launch_bounds__(64, 2) void jpeg_kernel(const float* __restrict__ in,
                                                     float* __restrict__ out) {
    __shared__ double sYd[64];   // level-shifted channel values (f64)
    __shared__ float sF[64];     // dequantized*alpha coefficients
    __shared__ float sG[64];     // idct stage-1 intermediate
    __shared__ float sC[64];     // fp32 cosine table c[x][u]

    const int lane = threadIdx.x;        // 0..63
    const int px = lane >> 3;            // pixel row within block
    const int py = lane & 7;             // pixel col within block

    sC[lane] = C32F.c[lane];

    // This lane's DCT table row (uv = lane): 128 VGPRs, loaded once.
    double T[64];
    #pragma unroll
    for (int i = 0; i < 64; ++i) T[i] = DCTT.t[lane][i];

    const double m   = QD.m[lane];
    const double qty = QD.qty[lane], qtc = QD.qtc[lane];
    const double dqy = QD.dqy[lane], dqc = QD.dqc[lane];

    int B = blockIdx.x;
    #pragma unroll 1
    for (int it = 0; it < ITERS; ++it, B += NWG) {
        const int b = B >> 12;
        const int blk = B & 4095;
        const int by = blk >> 6;
        const int bx = blk & 63;
        const size_t base = (size_t)b * 3 * PLANE + (size_t)(by * 8 + px) * WW
                          + (size_t)(bx * 8) + py;

        // ---- load this lane's pixel, fp64 color transform (R7-identical) ----
        const float Rf = in[base];
        const float Gf = in[base + PLANE];
        const float Bf = in[base + 2 * (size_t)PLANE];
        const double rv = ((double)Rf + 1.0) * 127.5;
        const double gv = ((double)Gf + 1.0) * 127.5;
        const double bv = ((double)Bf + 1.0) * 127.5;
        double yv = ((double)0.299f * rv + (double)0.587f * gv) + (double)0.114f * bv;
        yv = yv - 128.0;
        double cbv = ((double)-0.168736f * rv + (double)-0.331264f * gv) + (double)0.5f * bv;
        cbv = (cbv + 128.0) - 128.0;
        double crv = ((double)0.5f * rv + (double)-0.418688f * gv) + (double)-0.081312f * bv;
        crv = (crv + 128.0) - 128.0;

        float rec0, rec1, rec2;
        #pragma unroll
        for (int ch = 0; ch < 3; ++ch) {
            __syncthreads();   // protect sYd/sF/sG reuse from previous channel/iter
            sYd[lane] = (ch == 0) ? yv : (ch == 1 ? cbv : crv);
            __syncthreads();

            // ---- fp64 DCT dot (decision path — numerically identical to R7) ----
            double a0 = 0.0, a1 = 0.0, a2 = 0.0, a3 = 0.0;
            #pragma unroll
            for (int i = 0; i < 16; ++i) {
                a0 = __builtin_fma(T[i],      sYd[i],      a0);
                a1 = __builtin_fma(T[i + 16], sYd[i + 16], a1);
                a2 = __builtin_fma(T[i + 32], sYd[i + 32], a2);
                a3 = __builtin_fma(T[i + 48], sYd[i + 48], a3);
            }
            const double S = (a0 + a1) + (a2 + a3);
            const double qtd = (ch == 0) ? qty : qtc;
            const double dq  = (ch == 0) ? dqy : dqc;
            const double f = (m * S) / qtd;          // true f64 divide (as R7)
            const double rr = __builtin_rint(f);     // half-to-even
            const double d = f - rr;
            const float Fv = (float)((rr + (d * d) * d) * dq);

            __syncthreads();
            sF[lane] = Fv;
            __syncthreads();

            // ---- smooth fp32 separable IDCT, LDS-staged ----
            // stage 1: lane = (u, yy): G[u][yy] = sum_v c[yy][v] * F[u][v]
            {
                const int uu = lane >> 3, yy = lane & 7;
                float g = 0.0f;
                #pragma unroll
                for (int v = 0; v < 8; ++v) g += sC[yy * 8 + v] * sF[uu * 8 + v];
                __syncthreads();
                sG[lane] = g;
            }
            __syncthreads();
            // stage 2: lane = (px, py): P = 0.25 * sum_u c[px][u] * G[u][py]
            {
                float p = 0.0f;
                #pragma unroll
                for (int u = 0; u < 8; ++u) p += sC[px * 8 + u] * sG[u * 8 + py];
                p *= 0.25f;
                if (ch == 0) rec0 = p; else if (ch == 1) rec1 = p; else rec2 = p;
            }
        }

        // ---- YCbCr -> RGB, clip, /255, store (R7-identical formulas) ----
        const float yvf = rec0 + 128.0f;
        const float cb = rec1;
        const float cr = rec2;
        const float ro = yvf + 1.402f * cr;
        const float go = yvf - 0.344136f * cb - 0.714136f * cr;
        const float bo = yvf + 1.772f * cb;
        out[base]                     = fminf(fmaxf(ro, 0.0f), 255.0f) * (1.0f / 255.0f);
        out[base + PLANE]             = fminf(fmaxf(go, 0.0f), 255.0f) * (1.0f / 255.0f);
        out[base + 2 * (size_t)PLANE] = fminf(fmaxf(bo, 0.0f), 255.0f) * (1.0f / 255.0f);
    }
}

extern "C" void kernel_launch(void* const* d_in, const int* in_sizes, int n_in,
                              void* d_out, int out_size, void* d_ws, size_t ws_size,
                              hipStream_t stream) {
    const float* in = (const float*)d_in[0];
    float* out = (float*)d_out;
    jpeg_kernel<<<NWG, 64, 0, stream>>>(in, out);
}

// Round 9
// 179.066 us; speedup vs baseline: 1.5173x; 1.0459x over previous
//
#include <hip/hip_runtime.h>

namespace {

constexpr int BATCH = 16;
constexpr int HH = 512;
constexpr int WW = 512;
constexpr int PLANE = HH * WW;
constexpr int NPAIR = BATCH * (HH / 8) * (WW / 16);  // 32768 block-pairs
constexpr int NWG = 4096;                            // single-wave workgroups
constexpr int ITERS = NPAIR / NWG;                   // 8 pairs per wave

// ---- numpy-faithful cosine table (DO NOT TOUCH — decision-path numerics) ----
// cx[x,u] = fl32( cos( widen(fl32(K * fl32(pi))) / 16 ) ), K = (2x+1)*u
// dct_T[x,y,u,v] = fl32( cx[x,u] * cx[y,v] ), widened to f64 for contraction.
constexpr double PI64 = 3.141592653589793;
constexpr double PI_LO = 1.2246467991473532e-16;
constexpr double PI_HI = (double)((long long)(PI64 * 17592186044416.0)) / 17592186044416.0;
constexpr double PI_MID = PI64 - PI_HI;

constexpr double CD9[9] = {
    1.0,
    0.9807852804032304491,
    0.9238795325112867561,
    0.8314696123025452371,
    0.7071067811865475244,
    0.5555702330196022248,
    0.3826834323650897717,
    0.1950903220161282678,
    0.0};
constexpr double cos_tab(int m) {
    m %= 32;
    double s = 1.0;
    if (m > 16) m = 32 - m;
    if (m > 8) { s = -1.0; m = 16 - m; }
    return s * CD9[m];
}
constexpr double sin_tab(int m) { return cos_tab(m + 24); }

constexpr double cx64(int K) {
    float Kf = (float)K;
    float p32 = (float)PI64;
    float t32 = Kf * p32;
    double F = (double)t32;
    double E = ((F - (double)K * PI_HI) - (double)K * PI_MID) - (double)K * PI_LO;
    double r = E / 16.0;
    double C = cos_tab(K), S = sin_tab(K);
    double cr = 1.0 - 0.5 * r * r;
    double sr = r - (r * r * r) / 6.0;
    return C * cr - S * sr;
}
constexpr float cx32(int x, int u) { return (float)cx64((2 * x + 1) * u); }

struct DctTbl { double t[64][64]; };
constexpr DctTbl make_dct() {
    DctTbl T{};
    for (int u = 0; u < 8; ++u)
        for (int v = 0; v < 8; ++v)
            for (int x = 0; x < 8; ++x)
                for (int y = 0; y < 8; ++y)
                    T.t[u * 8 + v][x * 8 + y] = (double)(cx32(x, u) * cx32(y, v));
    return T;
}
constexpr DctTbl DCTT = make_dct();

struct C32A { float c[64]; };
constexpr C32A make_c32f() {
    C32A a{};
    for (int x = 0; x < 8; ++x)
        for (int u = 0; u < 8; ++u)
            a.c[x * 8 + u] = cx32(x, u);
    return a;
}
constexpr C32A C32F = make_c32f();

constexpr float YQ[64] = {
    16, 11, 10, 16, 24, 40, 51, 61,
    12, 12, 14, 19, 26, 58, 60, 55,
    14, 13, 16, 24, 40, 57, 69, 56,
    14, 17, 22, 29, 51, 87, 80, 62,
    18, 22, 37, 56, 68, 109, 103, 77,
    24, 35, 55, 64, 81, 104, 113, 92,
    49, 64, 78, 87, 103, 121, 120, 101,
    72, 92, 95, 98, 112, 100, 103, 99};

constexpr float CQ[64] = {
    17, 18, 24, 47, 99, 99, 99, 99,
    18, 21, 26, 66, 99, 99, 99, 99,
    24, 26, 56, 99, 99, 99, 99, 99,
    47, 66, 99, 99, 99, 99, 99, 99,
    99, 99, 99, 99, 99, 99, 99, 99,
    99, 99, 99, 99, 99, 99, 99, 99,
    99, 99, 99, 99, 99, 99, 99, 99,
    99, 99, 99, 99, 99, 99, 99, 99};

constexpr float AL32 = (float)0.7071067811865475244;

struct QuantD { double m[64]; double qty[64]; double qtc[64]; double dqy[64]; double dqc[64]; };
constexpr QuantD make_qd() {
    QuantD q{};
    for (int u = 0; u < 8; ++u)
        for (int v = 0; v < 8; ++v) {
            int i = u * 8 + v;
            float aa = (u == 0 ? AL32 : 1.0f) * (v == 0 ? AL32 : 1.0f);
            q.m[i]   = (double)(aa * 0.25f);
            q.qty[i] = (double)YQ[i];
            q.qtc[i] = (double)CQ[i];
            q.dqy[i] = (double)YQ[i] * (double)aa;
            q.dqc[i] = (double)CQ[i] * (double)aa;
        }
    return q;
}
constexpr QuantD QD = make_qd();

} // namespace

// fp64 color transform — bit-identical to R7/R8 (decision path).
__device__ __forceinline__ void color_f64(float Rf, float Gf, float Bf,
                                          double& yv, double& cbv, double& crv) {
    const double rv = ((double)Rf + 1.0) * 127.5;
    const double gv = ((double)Gf + 1.0) * 127.5;
    const double bv = ((double)Bf + 1.0) * 127.5;
    yv = ((double)0.299f * rv + (double)0.587f * gv) + (double)0.114f * bv;
    yv = yv - 128.0;
    cbv = ((double)-0.168736f * rv + (double)-0.331264f * gv) + (double)0.5f * bv;
    cbv = (cbv + 128.0) - 128.0;
    crv = ((double)0.5f * rv + (double)-0.418688f * gv) + (double)-0.081312f * bv;
    crv = (crv + 128.0) - 128.0;
}

// One wave = one PAIR of horizontally adjacent 8x8 blocks per iteration.
// Lanes: pixel (px,py) for load/idct/store; coefficient uv=lane for DCT/quant.
__global__ __launch_bounds__(64, 2) void jpeg_kernel(const float* __restrict__ in,
                                                     float* __restrict__ out) {
    __shared__ double sYd[2][3][64];  // pair x channel x spatial (f64)
    __shared__ float sF[2][3][64];    // dequantized*alpha coefficients
    __shared__ float sG[2][3][64];    // idct stage-1 intermediate
    __shared__ float sC[64];          // fp32 cosines c[x][u]

    const int lane = threadIdx.x;     // 0..63
    const int px = lane >> 3;         // row within block
    const int py = lane & 7;          // col index (block A: py, block B: 8+py)

    sC[lane] = C32F.c[lane];

    // This lane's DCT table row (uv = lane): 128 VGPRs, loaded once, L2-hot.
    double T[64];
    #pragma unroll
    for (int i = 0; i < 64; ++i) T[i] = DCTT.t[lane][i];

    const double m   = QD.m[lane];
    const double qty = QD.qty[lane], qtc = QD.qtc[lane];
    const double dqy = QD.dqy[lane], dqc = QD.dqc[lane];

    // Loaded float2 covers cols 2py,2py+1 of the 16-wide pair span:
    const int blkL = py >> 2;         // which block those pixels belong to
    const int col0 = (py & 3) * 2;    // column within that block

    int P = blockIdx.x;
    #pragma unroll 1
    for (int it = 0; it < ITERS; ++it, P += NWG) {
        const int b = P >> 11;              // image (2048 pairs per image)
        const int p2 = P & 2047;
        const int by = p2 >> 5;             // block row (64 rows)
        const int pbx = p2 & 31;            // pair col (32 pairs per row)
        const size_t rowbase = (size_t)b * 3 * PLANE + (size_t)(by * 8 + px) * WW
                             + (size_t)(pbx * 16);

        // ---- full-cache-line loads: float2 per lane per channel ----
        const float2 Rp = *(const float2*)(in + rowbase + 2 * py);
        const float2 Gp = *(const float2*)(in + rowbase + PLANE + 2 * py);
        const float2 Bp = *(const float2*)(in + rowbase + 2 * (size_t)PLANE + 2 * py);

        __syncthreads();   // prior iteration's DCT dots are done with sYd

        {
            double y0, cb0, cr0, y1, cb1, cr1;
            color_f64(Rp.x, Gp.x, Bp.x, y0, cb0, cr0);
            color_f64(Rp.y, Gp.y, Bp.y, y1, cb1, cr1);
            const int si = px * 8 + col0;
            *(double2*)&sYd[blkL][0][si] = make_double2(y0, y1);
            *(double2*)&sYd[blkL][1][si] = make_double2(cb0, cb1);
            *(double2*)&sYd[blkL][2][si] = make_double2(cr0, cr1);
        }
        __syncthreads();

        // ---- 6 independent fp64 DCT dots + diff-round quant (decision path:
        //      structure bit-identical to R7/R8) ----
        float Fv[2][3];
        #pragma unroll
        for (int blk = 0; blk < 2; ++blk) {
            #pragma unroll
            for (int ch = 0; ch < 3; ++ch) {
                const double* Yp = &sYd[blk][ch][0];
                double a0 = 0.0, a1 = 0.0, a2 = 0.0, a3 = 0.0;
                #pragma unroll
                for (int i = 0; i < 16; ++i) {
                    a0 = __builtin_fma(T[i],      Yp[i],      a0);
                    a1 = __builtin_fma(T[i + 16], Yp[i + 16], a1);
                    a2 = __builtin_fma(T[i + 32], Yp[i + 32], a2);
                    a3 = __builtin_fma(T[i + 48], Yp[i + 48], a3);
                }
                const double S = (a0 + a1) + (a2 + a3);
                const double qtd = (ch == 0) ? qty : qtc;
                const double dq  = (ch == 0) ? dqy : dqc;
                const double f = (m * S) / qtd;        // true f64 divide
                const double rr = __builtin_rint(f);   // half-to-even
                const double d = f - rr;
                Fv[blk][ch] = (float)((rr + (d * d) * d) * dq);
            }
        }
        #pragma unroll
        for (int blk = 0; blk < 2; ++blk)
            #pragma unroll
            for (int ch = 0; ch < 3; ++ch)
                sF[blk][ch][lane] = Fv[blk][ch];
        __syncthreads();

        // ---- smooth fp32 separable IDCT, LDS-staged, 6 matrices ----
        {
            const int uu = lane >> 3, yy = lane & 7;
            #pragma unroll
            for (int blk = 0; blk < 2; ++blk)
                #pragma unroll
                for (int ch = 0; ch < 3; ++ch) {
                    float g = 0.0f;
                    #pragma unroll
                    for (int v = 0; v < 8; ++v)
                        g += sC[yy * 8 + v] * sF[blk][ch][uu * 8 + v];
                    sG[blk][ch][lane] = g;
                }
        }
        __syncthreads();

        // stage 2 + color-back + stores, per block of the pair
        #pragma unroll
        for (int blk = 0; blk < 2; ++blk) {
            float rec[3];
            #pragma unroll
            for (int ch = 0; ch < 3; ++ch) {
                float p = 0.0f;
                #pragma unroll
                for (int u = 0; u < 8; ++u)
                    p += sC[px * 8 + u] * sG[blk][ch][u * 8 + py];
                rec[ch] = p * 0.25f;
            }
            const float yvf = rec[0] + 128.0f;
            const float cb = rec[1];
            const float cr = rec[2];
            const float ro = yvf + 1.402f * cr;
            const float go = yvf - 0.344136f * cb - 0.714136f * cr;
            const float bo = yvf + 1.772f * cb;
            const size_t ob = rowbase + blk * 8 + py;
            out[ob]                     = fminf(fmaxf(ro, 0.0f), 255.0f) * (1.0f / 255.0f);
            out[ob + PLANE]             = fminf(fmaxf(go, 0.0f), 255.0f) * (1.0f / 255.0f);
            out[ob + 2 * (size_t)PLANE] = fminf(fmaxf(bo, 0.0f), 255.0f) * (1.0f / 255.0f);
        }
    }
}

extern "C" void kernel_launch(void* const* d_in, const int* in_sizes, int n_in,
                              void* d_out, int out_size, void* d_ws, size_t ws_size,
                              hipStream_t stream) {
    const float* in = (const float*)d_in[0];
    float* out = (float*)d_out;
    jpeg_kernel<<<NWG, 64, 0, stream>>>(in, out);
}